// Round 1
// baseline (385.214 us; speedup 1.0000x reference)
//
#include <hip/hip_runtime.h>
#include <stdint.h>

// DISCO equidistant conv2d: depthwise 5x5, stride 2, zero pad 2.
// x: (4,16,1024,1024) f32, weight: (16,1,3) f32, bias: (16,) f32, psi: (3,5,5) f32
// out: (4,16,512,512) f32
//
// out[b,o,i,j] = bias[o] + sum_{dy,dx} K[o,dy,dx] * X(b,o, 2i+dy-2, 2j+dx-2)
// K[o,dy,dx]  = QW * sum_k weight[o,k] * psi[k,dy,dx]
//
// Tile: 8 out-rows x 128 out-cols per block -> 19 staged in-rows x 264 floats.
// vs previous 4x256: vertical halo redundancy 1.375 -> 1.1875 (-12% staged
// HBM fetch), LDS 22.9 KB -> 19.6 KB -> 8 blocks/CU (32 waves/CU, was 7/28).

#define H_IN   1024
#define W_IN   1024
#define H_OUT  512
#define W_OUT  512
#define CCH    16
#define NRB    3
#define PSIW   5
#define ROWS_OUT 8
#define ROWS_IN  19                   // 2*ROWS_OUT + 3
#define COLS_OUT 128
#define LROW     264                  // floats per LDS row; l -> x col = x0 + l
#define CHUNKS_PER_ROW (LROW / 4)     // 66 float4 chunks
#define NCHUNK   (ROWS_IN * CHUNKS_PER_ROW)   // 1254
#define QW 3.814697265625e-06f        // 2*2/(1024*1024)

typedef float vf2 __attribute__((ext_vector_type(2)));   // native vector for nontemporal store

__global__ __launch_bounds__(256) void disco_conv_kernel(
    const float* __restrict__ x,
    const float* __restrict__ weight,
    const float* __restrict__ bias,
    const float* __restrict__ psi,
    float* __restrict__ out)
{
    __shared__ __align__(16) float tile[ROWS_IN * LROW];   // 20064 B
    __shared__ float kbuf[32];

    const int t  = threadIdx.x;          // 0..255
    const int bx = blockIdx.x;           // 256 = 4 col-tiles * 64 row-tiles
    const int ct = bx & 3;
    const int rt = bx >> 2;
    const int o  = blockIdx.y;
    const int b  = blockIdx.z;

    const int i0 = rt * ROWS_OUT;        // first output row
    const int j0 = ct * COLS_OUT;        // first output col
    const int x0 = 2 * j0 - 4;           // x col of LDS l=0 (16B-aligned chunks)
    const int y0 = 2 * i0 - 2;           // x row of LDS rr=0

    const float* plane = x + (size_t)(b * CCH + o) * (H_IN * W_IN);

    // --- per-channel 5x5 kernel from basis coefficients (once per block) ---
    if (t < 25) {
        const int dy = t / 5, dx = t % 5;
        const float w0 = weight[o * NRB + 0];
        const float w1 = weight[o * NRB + 1];
        const float w2 = weight[o * NRB + 2];
        kbuf[t] = QW * (w0 * psi[(0 * PSIW + dy) * PSIW + dx] +
                        w1 * psi[(1 * PSIW + dy) * PSIW + dx] +
                        w2 * psi[(2 * PSIW + dy) * PSIW + dx]);
    }

    // --- stage 19 rows x 264 cols (coalesced float4, zero halo via predication) ---
    #pragma unroll
    for (int it = 0; it < 5; ++it) {
        const int q = t + it * 256;
        if (q < NCHUNK) {
            const int rr = q / CHUNKS_PER_ROW;        // magic-mul div
            const int m  = q - rr * CHUNKS_PER_ROW;
            const int y  = y0 + rr;
            const int xc = x0 + 4 * m;                // chunk never partially valid
            float4 v = make_float4(0.f, 0.f, 0.f, 0.f);
            if ((unsigned)y < (unsigned)H_IN && (unsigned)xc <= (unsigned)(W_IN - 4)) {
                v = *(const float4*)(plane + (size_t)y * W_IN + xc);
            }
            *(float4*)&tile[rr * LROW + 4 * m] = v;   // 16B-aligned
        }
    }
    __syncthreads();

    float K[25];
    #pragma unroll
    for (int n = 0; n < 25; ++n) K[n] = kbuf[n];      // broadcast reads

    // thread t -> out cols j0 + {2c, 2c+1}, out rows i0 + 2*rho + {0,1} (rho = 0..3)
    const int c   = t & 63;
    const int rho = t >> 6;
    const float bo = bias[o];
    float a00 = bo, a01 = bo;    // row s=0, cols 0/1
    float a10 = bo, a11 = bo;    // row s=1, cols 0/1

    // x row rr = 4*rho + 2*s + dy ; local l window = 4c + 2 .. 4c + 8
    const float* base = &tile[(4 * rho) * LROW + 4 * c];
    #pragma unroll
    for (int rl = 0; rl < 7; ++rl) {
        const float* row = base + rl * LROW;
        const float4 va = *(const float4*)(row);       // f0..f3 (16B aligned)
        const float4 vb = *(const float4*)(row + 4);   // f4..f7
        const float2 vc = *(const float2*)(row + 8);   // f8,f9
        const float f[10] = { va.x, va.y, va.z, va.w,
                              vb.x, vb.y, vb.z, vb.w,
                              vc.x, vc.y };
        if (rl < 5) {                                  // s=0, dy=rl
            #pragma unroll
            for (int dx = 0; dx < 5; ++dx) {
                const float kv = K[rl * 5 + dx];
                a00 += kv * f[2 + dx];
                a01 += kv * f[4 + dx];
            }
        }
        if (rl >= 2) {                                 // s=1, dy=rl-2
            #pragma unroll
            for (int dx = 0; dx < 5; ++dx) {
                const float kv = K[(rl - 2) * 5 + dx];
                a10 += kv * f[2 + dx];
                a11 += kv * f[4 + dx];
            }
        }
    }

    // --- coalesced nontemporal float2 stores (don't pollute L2/L3) ---
    float* oplane = out + (size_t)(b * CCH + o) * (H_OUT * W_OUT);
    const size_t o0 = (size_t)(i0 + 2 * rho) * W_OUT + j0 + 2 * c;
    vf2 s0; s0.x = a00; s0.y = a01;
    vf2 s1; s1.x = a10; s1.y = a11;
    __builtin_nontemporal_store(s0, (vf2*)(oplane + o0));
    __builtin_nontemporal_store(s1, (vf2*)(oplane + o0 + W_OUT));
}

extern "C" void kernel_launch(void* const* d_in, const int* in_sizes, int n_in,
                              void* d_out, int out_size, void* d_ws, size_t ws_size,
                              hipStream_t stream) {
    const float* x      = (const float*)d_in[0];
    const float* weight = (const float*)d_in[1];
    const float* bias   = (const float*)d_in[2];
    const float* psi    = (const float*)d_in[3];
    float* out          = (float*)d_out;

    dim3 grid(4 * (H_OUT / ROWS_OUT), CCH, 4);   // (256, 16, 4) = 16384 blocks
    disco_conv_kernel<<<grid, 256, 0, stream>>>(x, weight, bias, psi, out);
}